// Round 9
// baseline (216.747 us; speedup 1.0000x reference)
//
#include <hip/hip_runtime.h>
#include <math.h>

// GAT multi-head attention conv, MI355X. Round 9 (= round 8 resubmitted;
// round 8 never ran: GPU acquisition timeout).
// prep (wt bf16 swizzled + va=W@a) -> s2 (register va, wave=2 nodes)
// -> mms (src-only bf16 MFMA GEMM || XCD-range-owned edge scatter, 16B entries)
// -> gather (broadcast uint4 entries, 4x-unrolled MLP, no shfl).
constexpr int N_SRC_ = 50000;
constexpr int N_DST_ = 50000;
constexpr int N_TOT_ = 100000;   // s rows: src [0,50000), dst [50000,100000)
constexpr int E_     = 640000;
constexpr int D_     = 128;
constexpr int CAP_   = 64;       // bucket capacity; max degree ~38 (Poisson 12.8)
constexpr int NTILE  = (N_SRC_ + 31) / 32;   // 1563 src row-tiles
constexpr int MMB    = (NTILE + 3) / 4;      // 391 mm blocks (4 wave-tiles each)
constexpr int NCHUNK = (E_ + 2047) / 2048;   // 313 edge chunks
constexpr int SCB    = NCHUNK * 8;           // 2504 scatter blocks (chunk x range)
constexpr int DPR    = N_DST_ / 8;           // 6250 dst nodes per range

typedef float f32x4  __attribute__((ext_vector_type(4)));
typedef short bf16x8 __attribute__((ext_vector_type(8)));

union U4 { unsigned int u[4]; bf16x8 v; };

// round-to-nearest-even float -> bf16 bits
static __device__ __forceinline__ unsigned short f2bf_rne(float f) {
    unsigned int x = __float_as_uint(f);
    return (unsigned short)((x + 0x7FFFu + ((x >> 16) & 1u)) >> 16);
}

// ---------------------------------------------------------------------------
// K0: wt = swizzled bf16 W^T (n-major, k contiguous; chunk c of 8 k-elems at
// slot c^(n&15) -> conflict-free b128 LDS reads), va[k][col] fp32 with
// col = half*4+head: va = W @ a_half per head.
__global__ __launch_bounds__(256) void k_prep(
    const float* __restrict__ W, const float* __restrict__ a,
    unsigned short* __restrict__ wt, float* __restrict__ va)
{
    int tid = blockIdx.x * 256 + threadIdx.x;
    if (tid >= 136 * 16) return;
    int n = tid >> 4, c = tid & 15;
    if (n < 128) {
        int slot = c ^ (n & 15);
        size_t base = (size_t)n * 128 + slot * 8;
#pragma unroll
        for (int j = 0; j < 8; ++j) {
            int k = c * 8 + j;
            wt[base + j] = f2bf_rne(W[(size_t)k * 128 + n]);
        }
    } else {
        int col = n - 128, half = col >> 2, hd = col & 3;
#pragma unroll
        for (int j = 0; j < 8; ++j) {
            int k = c * 8 + j;
            float acc = 0.f;
            for (int c2 = 0; c2 < 32; ++c2)
                acc += W[(size_t)k * 128 + hd * 32 + c2] * a[half * 32 + c2];
            va[(size_t)k * 8 + col] = acc;
        }
    }
}

// ---------------------------------------------------------------------------
// K1: s[node][hd] = <feat[node], va[:, half*4+hd]> fp32, all 100K nodes.
// Wave handles 2 nodes (32 lanes each); va held in registers (no LDS, no
// barriers); 5-step butterfly reduce within each 32-lane group.
__global__ __launch_bounds__(256) void k_s2(
    const float* __restrict__ src, const float* __restrict__ dst,
    const float* __restrict__ va, float* __restrict__ s)
{
    const int gw = (blockIdx.x * 256 + threadIdx.x) >> 6;  // 0..2047
    const int lane = threadIdx.x & 63;
    const int l32 = lane & 31, hf = lane >> 5;

    float4 vs[4], vd[4];   // va rows 4*l32..+3, src half / dst half
#pragma unroll
    for (int j = 0; j < 4; ++j) {
        const float* vp = va + (size_t)(4 * l32 + j) * 8;
        vs[j] = *(const float4*)vp;
        vd[j] = *(const float4*)(vp + 4);
    }

    for (int p = gw; p < N_TOT_ / 2; p += 2048) {
        int node = p * 2 + hf;
        bool is_src = node < N_SRC_;
        const float* f = is_src ? src + (size_t)node * D_
                                : dst + (size_t)(node - N_SRC_) * D_;
        float4 x = *(const float4*)(f + l32 * 4);
        float4 v0 = is_src ? vs[0] : vd[0];
        float4 v1 = is_src ? vs[1] : vd[1];
        float4 v2 = is_src ? vs[2] : vd[2];
        float4 v3 = is_src ? vs[3] : vd[3];
        float a0 = x.x * v0.x + x.y * v1.x + x.z * v2.x + x.w * v3.x;
        float a1 = x.x * v0.y + x.y * v1.y + x.z * v2.y + x.w * v3.y;
        float a2 = x.x * v0.z + x.y * v1.z + x.z * v2.z + x.w * v3.z;
        float a3 = x.x * v0.w + x.y * v1.w + x.z * v2.w + x.w * v3.w;
#pragma unroll
        for (int m = 1; m < 32; m <<= 1) {
            a0 += __shfl_xor(a0, m, 64);
            a1 += __shfl_xor(a1, m, 64);
            a2 += __shfl_xor(a2, m, 64);
            a3 += __shfl_xor(a3, m, 64);
        }
        if (l32 == 0)
            *(float4*)&s[(size_t)node * 4] = make_float4(a0, a1, a2, a3);
    }
}

// ---------------------------------------------------------------------------
// K2 fused. Blocks [0,MMB): h = src_feat @ W (bf16 MFMA).
// Blocks [MMB,MMB+SCB): range-owned scatter — block (chunk, r) scans its
// 2048-edge chunk, processes only edges with dst/DPR == r. With round-robin
// block->XCD placement each bucket line + cursor atomic stays in one L2.
// Entry = uint4 {sn, w0|w1, w2|w3, 0} (single 16B line-touch per edge).
__global__ __launch_bounds__(256) void k_mms(
    const float* __restrict__ src, const unsigned short* __restrict__ wt,
    const int* __restrict__ src_idx, const int* __restrict__ dst_idx,
    const float* __restrict__ s,
    int* __restrict__ cursor, uint4* __restrict__ bucket,
    unsigned int* __restrict__ h)
{
    if (blockIdx.x >= MMB) {
        int bid = (int)blockIdx.x - MMB;
        int r = bid & 7;
        int ebase = (bid >> 3) * 2048 + threadIdx.x;
#pragma unroll
        for (int ii = 0; ii < 8; ++ii) {
            int e = ebase + ii * 256;
            if (e >= E_) break;
            int dn = dst_idx[e];
            if (dn / DPR != r) continue;     // not this range-owner
            int sn = src_idx[e];
            float4 vsv = *(const float4*)&s[(size_t)sn * 4];
            float4 vdv = *(const float4*)&s[(size_t)(N_SRC_ + dn) * 4];
            float x0 = vsv.x + vdv.x, x1 = vsv.y + vdv.y;
            float x2 = vsv.z + vdv.z, x3 = vsv.w + vdv.w;
            float w0 = __expf(x0 > 0.f ? x0 : (__expf(x0) - 1.f));
            float w1 = __expf(x1 > 0.f ? x1 : (__expf(x1) - 1.f));
            float w2 = __expf(x2 > 0.f ? x2 : (__expf(x2) - 1.f));
            float w3 = __expf(x3 > 0.f ? x3 : (__expf(x3) - 1.f));
            uint4 ent;
            ent.x = (unsigned int)sn;
            ent.y = (unsigned int)f2bf_rne(w0) | ((unsigned int)f2bf_rne(w1) << 16);
            ent.z = (unsigned int)f2bf_rne(w2) | ((unsigned int)f2bf_rne(w3) << 16);
            ent.w = 0u;
            int pos = atomicAdd(&cursor[dn], 1);
            if (pos < CAP_) bucket[(size_t)dn * CAP_ + pos] = ent;
        }
        return;
    }

    // ---- mm path ----
    __shared__ unsigned short wl[128 * 128];   // 32 KB
    const int t = threadIdx.x;
    {
        const float4* gw = (const float4*)wt;
        float4* sw = (float4*)wl;
#pragma unroll
        for (int i = 0; i < 8; ++i) sw[t + 256 * i] = gw[t + 256 * i];  // 2048
    }
    __syncthreads();

    const int wid = t >> 6, lane = t & 63;
    const int g = lane >> 4, sidx = lane & 15;
    const int wtile = blockIdx.x * 4 + wid;
    if (wtile >= NTILE) return;
    const int base = wtile * 32;
    const int r0 = base + sidx;                       // always < N_SRC_
    const int r1g = base + 16 + sidx;
    const int r1 = (r1g < N_SRC_) ? r1g : 0;          // clamp; stores guarded
    const float* p0 = src + (size_t)r0 * D_;
    const float* p1 = src + (size_t)r1 * D_;

    f32x4 acc[2][8];
#pragma unroll
    for (int m = 0; m < 2; ++m)
#pragma unroll
        for (int nf = 0; nf < 8; ++nf) acc[m][nf] = (f32x4)0.f;

#pragma unroll
    for (int ks = 0; ks < 4; ++ks) {
        const int k0 = ks * 32 + g * 8;   // this lane's 8-k slice
        bf16x8 af[2];
#pragma unroll
        for (int m = 0; m < 2; ++m) {
            const float* p = m ? p1 : p0;
            float4 v0 = *(const float4*)(p + k0);
            float4 v1 = *(const float4*)(p + k0 + 4);
            float f[8] = {v0.x, v0.y, v0.z, v0.w, v1.x, v1.y, v1.z, v1.w};
            U4 P;
#pragma unroll
            for (int q = 0; q < 4; ++q)
                P.u[q] = (unsigned int)f2bf_rne(f[2 * q])
                       | ((unsigned int)f2bf_rne(f[2 * q + 1]) << 16);
            af[m] = P.v;
        }
#pragma unroll
        for (int nf = 0; nf < 8; ++nf) {
            const int n = nf * 16 + sidx;             // col (n&15 == sidx)
            const int off = n * 128 + ((ks * 4 + g) ^ sidx) * 8;
            bf16x8 b = *(const bf16x8*)&wl[off];
            acc[0][nf] = __builtin_amdgcn_mfma_f32_16x16x32_bf16(af[0], b, acc[0][nf], 0, 0, 0);
            acc[1][nf] = __builtin_amdgcn_mfma_f32_16x16x32_bf16(af[1], b, acc[1][nf], 0, 0, 0);
        }
    }

    // Epilogue: C/D col = lane&15, row = g*4 + reg. h packed (col, col+16).
#pragma unroll
    for (int m = 0; m < 2; ++m) {
        const int rowb = base + m * 16 + g * 4;
#pragma unroll
        for (int r = 0; r < 4; ++r) {
            const int row = rowb + r;
            if (row < N_SRC_) {
#pragma unroll
                for (int q = 0; q < 4; ++q) {
                    unsigned int val = (unsigned int)f2bf_rne(acc[m][2 * q][r])
                                     | ((unsigned int)f2bf_rne(acc[m][2 * q + 1][r]) << 16);
                    h[(size_t)row * 64 + q * 16 + sidx] = val;
                }
            }
        }
    }
}

// ---------------------------------------------------------------------------
// K3: one wave per dst node. Lane l = 16*hd + sub owns out cols 32hd+sub and
// +16 (matches h packing). Per edge: one broadcast uint4 entry load (sn + w)
// + one h-row dword + 2 fma. Counted 4x-unrolled loop -> 4 h-loads in flight.
// All 16 head-lanes hold identical w -> den needs no cross-lane reduce.
__global__ __launch_bounds__(256) void k_gather(
    const unsigned int* __restrict__ h2, const int* __restrict__ cursor,
    const uint4* __restrict__ bucket, float* __restrict__ out)
{
    int wid = (blockIdx.x * 256 + threadIdx.x) >> 6;
    int lane = threadIdx.x & 63;
    if (wid >= N_DST_) return;
    int cnt = min(cursor[wid], CAP_);
    const int hd = lane >> 4;
    const int sub = lane & 15;
    const uint4* B = bucket + (size_t)wid * CAP_;

    auto wext = [&](const uint4& e) {
        unsigned int u = (hd & 2) ? e.z : e.y;
        return __uint_as_float((hd & 1) ? (u & 0xFFFF0000u) : (u << 16));
    };

    float2 A0 = make_float2(0.f, 0.f), A1 = A0, A2 = A0, A3 = A0;
    float d0 = 0.f, d1 = 0.f, d2 = 0.f, d3 = 0.f;
    int i = 0;
    for (; i + 4 <= cnt; i += 4) {
        uint4 e0 = B[i], e1 = B[i + 1], e2 = B[i + 2], e3 = B[i + 3];
        unsigned int v0 = h2[(size_t)e0.x * 64 + lane];
        unsigned int v1 = h2[(size_t)e1.x * 64 + lane];
        unsigned int v2 = h2[(size_t)e2.x * 64 + lane];
        unsigned int v3 = h2[(size_t)e3.x * 64 + lane];
        float w0 = wext(e0), w1 = wext(e1), w2 = wext(e2), w3 = wext(e3);
        d0 += w0; d1 += w1; d2 += w2; d3 += w3;
        A0.x = fmaf(w0, __uint_as_float(v0 << 16), A0.x);
        A0.y = fmaf(w0, __uint_as_float(v0 & 0xFFFF0000u), A0.y);
        A1.x = fmaf(w1, __uint_as_float(v1 << 16), A1.x);
        A1.y = fmaf(w1, __uint_as_float(v1 & 0xFFFF0000u), A1.y);
        A2.x = fmaf(w2, __uint_as_float(v2 << 16), A2.x);
        A2.y = fmaf(w2, __uint_as_float(v2 & 0xFFFF0000u), A2.y);
        A3.x = fmaf(w3, __uint_as_float(v3 << 16), A3.x);
        A3.y = fmaf(w3, __uint_as_float(v3 & 0xFFFF0000u), A3.y);
    }
    for (; i < cnt; ++i) {
        uint4 e = B[i];
        unsigned int v = h2[(size_t)e.x * 64 + lane];
        float w = wext(e);
        d0 += w;
        A0.x = fmaf(w, __uint_as_float(v << 16), A0.x);
        A0.y = fmaf(w, __uint_as_float(v & 0xFFFF0000u), A0.y);
    }

    float den = (d0 + d1) + (d2 + d3);
    float2 acc = make_float2((A0.x + A1.x) + (A2.x + A3.x),
                             (A0.y + A1.y) + (A2.y + A3.y));
    float inv = 1.f / (den + 1e-12f);
    out[(size_t)wid * D_ + 32 * hd + sub]      = acc.x * inv;
    out[(size_t)wid * D_ + 32 * hd + sub + 16] = acc.y * inv;
}

// ---------------------------------------------------------------------------
extern "C" void kernel_launch(void* const* d_in, const int* in_sizes, int n_in,
                              void* d_out, int out_size, void* d_ws, size_t ws_size,
                              hipStream_t stream)
{
    const float* src_feat = (const float*)d_in[0];
    const float* dst_feat = (const float*)d_in[1];
    const int*   edge     = (const int*)d_in[2];   // [2, E]
    const int*   src_idx  = edge;
    const int*   dst_idx  = edge + E_;
    const float* W        = (const float*)d_in[3];
    const float* a        = (const float*)d_in[4];
    float*       out      = (float*)d_out;

    char* p = (char*)d_ws;
    auto alloc = [&](size_t bytes) {
        char* r = p;
        p += (bytes + 255) & ~(size_t)255;
        return r;
    };
    unsigned int* h    = (unsigned int*)alloc((size_t)N_SRC_ * 64 * 4);        // 12.8 MB
    float*  s          = (float*)alloc((size_t)N_TOT_ * 4 * sizeof(float));    // 1.6 MB
    int*    cursor     = (int*)alloc((size_t)N_DST_ * sizeof(int));            // 0.2 MB
    uint4*  bucket     = (uint4*)alloc((size_t)N_DST_ * CAP_ * sizeof(uint4)); // 51.2 MB
    unsigned short* wt = (unsigned short*)alloc((size_t)128 * 128 * 2);        // 32 KB
    float*  va         = (float*)alloc((size_t)128 * 8 * sizeof(float));       // 4 KB

    hipMemsetAsync(cursor, 0, (size_t)N_DST_ * sizeof(int), stream);

    k_prep<<<(136 * 16 + 255) / 256, 256, 0, stream>>>(W, a, wt, va);
    k_s2<<<512, 256, 0, stream>>>(src_feat, dst_feat, va, s);
    k_mms<<<MMB + SCB, 256, 0, stream>>>(src_feat, wt, src_idx, dst_idx, s,
                                         cursor, bucket, h);
    k_gather<<<(N_DST_ * 64 + 255) / 256, 256, 0, stream>>>(
        h, cursor, bucket, out);
}

// Round 10
// 215.347 us; speedup vs baseline: 1.0065x; 1.0065x over previous
//
#include <hip/hip_runtime.h>
#include <math.h>

// GAT multi-head attention conv, MI355X. Round 10: attribution round.
// 4 dispatches: s2v (cursor-clear + va=W@a + s) -> mm (self-staging bf16 MFMA)
// -> scatter (simple, 16B entries) -> gather (8-deep MLP).
constexpr int N_SRC_ = 50000;
constexpr int N_DST_ = 50000;
constexpr int N_TOT_ = 100000;   // s rows: src [0,50000), dst [50000,100000)
constexpr int E_     = 640000;
constexpr int D_     = 128;
constexpr int CAP_   = 64;       // bucket capacity; max degree ~38 (Poisson 12.8)
constexpr int NTILE  = (N_SRC_ + 31) / 32;   // 1563 src row-tiles
constexpr int MMB    = (NTILE + 3) / 4;      // 391 mm blocks (4 wave-tiles each)

typedef float f32x4  __attribute__((ext_vector_type(4)));
typedef short bf16x8 __attribute__((ext_vector_type(8)));

union U4 { unsigned int u[4]; bf16x8 v; };

// round-to-nearest-even float -> bf16 bits
static __device__ __forceinline__ unsigned short f2bf_rne(float f) {
    unsigned int x = __float_as_uint(f);
    return (unsigned short)((x + 0x7FFFu + ((x >> 16) & 1u)) >> 16);
}

// ---------------------------------------------------------------------------
// K1: fused {cursor clear, va = W@a (per-block, into LDS), s-dots}.
// s[node][hd] = <feat[node], va[:, half*4+hd]>, fp32, all 100K nodes.
// Wave = 2 nodes (32 lanes each); va regs loaded from LDS; butterfly reduce.
__global__ __launch_bounds__(256) void k_s2v(
    const float* __restrict__ src, const float* __restrict__ dst,
    const float* __restrict__ W, const float* __restrict__ a,
    float* __restrict__ s, int* __restrict__ cursor)
{
    __shared__ float val[128 * 8];
    const int t = threadIdx.x;

    // cursor clear (grid-stride; 512*256 covers 50K)
    int cid = blockIdx.x * 256 + t;
    if (cid < N_DST_) cursor[cid] = 0;

    // va: thread t computes pairs t*4..t*4+3 of (k, col); col = half*4+hd.
#pragma unroll
    for (int j = 0; j < 4; ++j) {
        int pair = t * 4 + j;             // 0..1023
        int k = pair >> 3, col = pair & 7;
        int half = col >> 2, hd = col & 3;
        float acc = 0.f;
        for (int c2 = 0; c2 < 32; ++c2)
            acc += W[(size_t)k * 128 + hd * 32 + c2] * a[half * 32 + c2];
        val[k * 8 + col] = acc;
    }
    __syncthreads();

    const int gw = (blockIdx.x * 256 + t) >> 6;  // 0..2047
    const int lane = t & 63;
    const int l32 = lane & 31, hf = lane >> 5;

    float4 vs[4], vd[4];   // va rows 4*l32..+3 (one-time conflicted LDS read, ok)
#pragma unroll
    for (int j = 0; j < 4; ++j) {
        vs[j] = *(const float4*)&val[(4 * l32 + j) * 8];
        vd[j] = *(const float4*)&val[(4 * l32 + j) * 8 + 4];
    }

    for (int p = gw; p < N_TOT_ / 2; p += 2048) {
        int node = p * 2 + hf;
        bool is_src = node < N_SRC_;
        const float* f = is_src ? src + (size_t)node * D_
                                : dst + (size_t)(node - N_SRC_) * D_;
        float4 x = *(const float4*)(f + l32 * 4);
        float4 v0 = is_src ? vs[0] : vd[0];
        float4 v1 = is_src ? vs[1] : vd[1];
        float4 v2 = is_src ? vs[2] : vd[2];
        float4 v3 = is_src ? vs[3] : vd[3];
        float a0 = x.x * v0.x + x.y * v1.x + x.z * v2.x + x.w * v3.x;
        float a1 = x.x * v0.y + x.y * v1.y + x.z * v2.y + x.w * v3.y;
        float a2 = x.x * v0.z + x.y * v1.z + x.z * v2.z + x.w * v3.z;
        float a3 = x.x * v0.w + x.y * v1.w + x.z * v2.w + x.w * v3.w;
#pragma unroll
        for (int m = 1; m < 32; m <<= 1) {
            a0 += __shfl_xor(a0, m, 64);
            a1 += __shfl_xor(a1, m, 64);
            a2 += __shfl_xor(a2, m, 64);
            a3 += __shfl_xor(a3, m, 64);
        }
        if (l32 == 0)
            *(float4*)&s[(size_t)node * 4] = make_float4(a0, a1, a2, a3);
    }
}

// ---------------------------------------------------------------------------
// K2: h = src_feat @ W via mfma_f32_16x16x32_bf16. W converted bf16 + swizzled
// during LDS staging (no prep kernel): thread t owns col n=t>>1, half=t&1;
// chunk c (8 k-elems) stored at slot c^(n&15) -> conflict-free b128 reads.
__global__ __launch_bounds__(256) void k_mm(
    const float* __restrict__ src, const float* __restrict__ W,
    unsigned int* __restrict__ h)
{
    __shared__ unsigned short wl[128 * 128];   // 32 KB
    const int t = threadIdx.x;
    {
        const int n = t >> 1, half = t & 1;
#pragma unroll
        for (int c8 = 0; c8 < 8; ++c8) {
            int c = half * 8 + c8;
            U4 P;
#pragma unroll
            for (int q = 0; q < 4; ++q) {
                float f0 = W[(size_t)(c * 8 + 2 * q) * 128 + n];
                float f1 = W[(size_t)(c * 8 + 2 * q + 1) * 128 + n];
                P.u[q] = (unsigned int)f2bf_rne(f0)
                       | ((unsigned int)f2bf_rne(f1) << 16);
            }
            int slot = c ^ (n & 15);
            *(bf16x8*)&wl[n * 128 + slot * 8] = P.v;
        }
    }
    __syncthreads();

    const int wid = t >> 6, lane = t & 63;
    const int g = lane >> 4, sidx = lane & 15;
    const int wtile = blockIdx.x * 4 + wid;
    if (wtile >= NTILE) return;
    const int base = wtile * 32;
    const int r0 = base + sidx;                       // always < N_SRC_
    const int r1g = base + 16 + sidx;
    const int r1 = (r1g < N_SRC_) ? r1g : 0;          // clamp; stores guarded
    const float* p0 = src + (size_t)r0 * D_;
    const float* p1 = src + (size_t)r1 * D_;

    f32x4 acc[2][8];
#pragma unroll
    for (int m = 0; m < 2; ++m)
#pragma unroll
        for (int nf = 0; nf < 8; ++nf) acc[m][nf] = (f32x4)0.f;

#pragma unroll
    for (int ks = 0; ks < 4; ++ks) {
        const int k0 = ks * 32 + g * 8;   // this lane's 8-k slice
        bf16x8 af[2];
#pragma unroll
        for (int m = 0; m < 2; ++m) {
            const float* p = m ? p1 : p0;
            float4 v0 = *(const float4*)(p + k0);
            float4 v1 = *(const float4*)(p + k0 + 4);
            float f[8] = {v0.x, v0.y, v0.z, v0.w, v1.x, v1.y, v1.z, v1.w};
            U4 P;
#pragma unroll
            for (int q = 0; q < 4; ++q)
                P.u[q] = (unsigned int)f2bf_rne(f[2 * q])
                       | ((unsigned int)f2bf_rne(f[2 * q + 1]) << 16);
            af[m] = P.v;
        }
#pragma unroll
        for (int nf = 0; nf < 8; ++nf) {
            const int n = nf * 16 + sidx;             // col (n&15 == sidx)
            const int off = n * 128 + ((ks * 4 + g) ^ sidx) * 8;
            bf16x8 b = *(const bf16x8*)&wl[off];
            acc[0][nf] = __builtin_amdgcn_mfma_f32_16x16x32_bf16(af[0], b, acc[0][nf], 0, 0, 0);
            acc[1][nf] = __builtin_amdgcn_mfma_f32_16x16x32_bf16(af[1], b, acc[1][nf], 0, 0, 0);
        }
    }

    // Epilogue: C/D col = lane&15, row = g*4 + reg. h packed (col, col+16).
#pragma unroll
    for (int m = 0; m < 2; ++m) {
        const int rowb = base + m * 16 + g * 4;
#pragma unroll
        for (int r = 0; r < 4; ++r) {
            const int row = rowb + r;
            if (row < N_SRC_) {
#pragma unroll
                for (int q = 0; q < 4; ++q) {
                    unsigned int val = (unsigned int)f2bf_rne(acc[m][2 * q][r])
                                     | ((unsigned int)f2bf_rne(acc[m][2 * q + 1][r]) << 16);
                    h[(size_t)row * 64 + q * 16 + sidx] = val;
                }
            }
        }
    }
}

// ---------------------------------------------------------------------------
// K3: simple edge scatter. Entry = uint4 {sn, w0|w1, w2|w3, 0} (one 16B
// line-touch per edge) into fixed-capacity dst buckets via cursor atomics.
__global__ __launch_bounds__(256) void k_scatter(
    const int* __restrict__ src_idx, const int* __restrict__ dst_idx,
    const float* __restrict__ s,
    int* __restrict__ cursor, uint4* __restrict__ bucket)
{
    int e = blockIdx.x * 256 + threadIdx.x;   // grid exact: E_/256
    int sn = src_idx[e], dn = dst_idx[e];
    float4 vsv = *(const float4*)&s[(size_t)sn * 4];
    float4 vdv = *(const float4*)&s[(size_t)(N_SRC_ + dn) * 4];
    float x0 = vsv.x + vdv.x, x1 = vsv.y + vdv.y;
    float x2 = vsv.z + vdv.z, x3 = vsv.w + vdv.w;
    float w0 = __expf(x0 > 0.f ? x0 : (__expf(x0) - 1.f));   // exp(elu(x))
    float w1 = __expf(x1 > 0.f ? x1 : (__expf(x1) - 1.f));
    float w2 = __expf(x2 > 0.f ? x2 : (__expf(x2) - 1.f));
    float w3 = __expf(x3 > 0.f ? x3 : (__expf(x3) - 1.f));
    uint4 ent;
    ent.x = (unsigned int)sn;
    ent.y = (unsigned int)f2bf_rne(w0) | ((unsigned int)f2bf_rne(w1) << 16);
    ent.z = (unsigned int)f2bf_rne(w2) | ((unsigned int)f2bf_rne(w3) << 16);
    ent.w = 0u;
    int pos = atomicAdd(&cursor[dn], 1);
    if (pos < CAP_) bucket[(size_t)dn * CAP_ + pos] = ent;
}

// ---------------------------------------------------------------------------
// K4: one wave per dst node. Lane l = 16*hd + sub owns out cols 32hd+sub and
// +16 (matches h packing). Per edge: broadcast uint4 entry + one h-row dword
// + 2 fma. 8-deep unrolled main loop -> 8 h-loads in flight.
__global__ __launch_bounds__(256) void k_gather(
    const unsigned int* __restrict__ h2, const int* __restrict__ cursor,
    const uint4* __restrict__ bucket, float* __restrict__ out)
{
    int wid = (blockIdx.x * 256 + threadIdx.x) >> 6;
    int lane = threadIdx.x & 63;
    if (wid >= N_DST_) return;
    int cnt = min(cursor[wid], CAP_);
    const int hd = lane >> 4;
    const int sub = lane & 15;
    const uint4* B = bucket + (size_t)wid * CAP_;

    auto wext = [&](const uint4& e) {
        unsigned int u = (hd & 2) ? e.z : e.y;
        return __uint_as_float((hd & 1) ? (u & 0xFFFF0000u) : (u << 16));
    };

    float2 A[4] = {make_float2(0.f, 0.f), make_float2(0.f, 0.f),
                   make_float2(0.f, 0.f), make_float2(0.f, 0.f)};
    float dacc[4] = {0.f, 0.f, 0.f, 0.f};

    int i = 0;
    for (; i + 8 <= cnt; i += 8) {
        uint4 e[8];
        unsigned int v[8];
#pragma unroll
        for (int j = 0; j < 8; ++j) e[j] = B[i + j];
#pragma unroll
        for (int j = 0; j < 8; ++j) v[j] = h2[(size_t)e[j].x * 64 + lane];
#pragma unroll
        for (int j = 0; j < 8; ++j) {
            float w = wext(e[j]);
            dacc[j & 3] += w;
            A[j & 3].x = fmaf(w, __uint_as_float(v[j] << 16), A[j & 3].x);
            A[j & 3].y = fmaf(w, __uint_as_float(v[j] & 0xFFFF0000u), A[j & 3].y);
        }
    }
    for (; i + 4 <= cnt; i += 4) {
        uint4 e[4];
        unsigned int v[4];
#pragma unroll
        for (int j = 0; j < 4; ++j) e[j] = B[i + j];
#pragma unroll
        for (int j = 0; j < 4; ++j) v[j] = h2[(size_t)e[j].x * 64 + lane];
#pragma unroll
        for (int j = 0; j < 4; ++j) {
            float w = wext(e[j]);
            dacc[j] += w;
            A[j].x = fmaf(w, __uint_as_float(v[j] << 16), A[j].x);
            A[j].y = fmaf(w, __uint_as_float(v[j] & 0xFFFF0000u), A[j].y);
        }
    }
    for (; i < cnt; ++i) {
        uint4 e = B[i];
        unsigned int v = h2[(size_t)e.x * 64 + lane];
        float w = wext(e);
        dacc[0] += w;
        A[0].x = fmaf(w, __uint_as_float(v << 16), A[0].x);
        A[0].y = fmaf(w, __uint_as_float(v & 0xFFFF0000u), A[0].y);
    }

    float den = (dacc[0] + dacc[1]) + (dacc[2] + dacc[3]);
    float2 acc = make_float2((A[0].x + A[1].x) + (A[2].x + A[3].x),
                             (A[0].y + A[1].y) + (A[2].y + A[3].y));
    float inv = 1.f / (den + 1e-12f);
    out[(size_t)wid * D_ + 32 * hd + sub]      = acc.x * inv;
    out[(size_t)wid * D_ + 32 * hd + sub + 16] = acc.y * inv;
}

// ---------------------------------------------------------------------------
extern "C" void kernel_launch(void* const* d_in, const int* in_sizes, int n_in,
                              void* d_out, int out_size, void* d_ws, size_t ws_size,
                              hipStream_t stream)
{
    const float* src_feat = (const float*)d_in[0];
    const float* dst_feat = (const float*)d_in[1];
    const int*   edge     = (const int*)d_in[2];   // [2, E]
    const int*   src_idx  = edge;
    const int*   dst_idx  = edge + E_;
    const float* W        = (const float*)d_in[3];
    const float* a        = (const float*)d_in[4];
    float*       out      = (float*)d_out;

    char* p = (char*)d_ws;
    auto alloc = [&](size_t bytes) {
        char* r = p;
        p += (bytes + 255) & ~(size_t)255;
        return r;
    };
    unsigned int* h = (unsigned int*)alloc((size_t)N_SRC_ * 64 * 4);          // 12.8 MB
    float* s        = (float*)alloc((size_t)N_TOT_ * 4 * sizeof(float));      // 1.6 MB
    int*   cursor   = (int*)alloc((size_t)N_DST_ * sizeof(int));              // 0.2 MB
    uint4* bucket   = (uint4*)alloc((size_t)N_DST_ * CAP_ * sizeof(uint4));   // 51.2 MB

    k_s2v<<<512, 256, 0, stream>>>(src_feat, dst_feat, W, a, s, cursor);
    k_mm<<<MMB, 256, 0, stream>>>(src_feat, W, h);
    k_scatter<<<E_ / 256, 256, 0, stream>>>(src_idx, dst_idx, s, cursor, bucket);
    k_gather<<<(N_DST_ * 64 + 255) / 256, 256, 0, stream>>>(
        h, cursor, bucket, out);
}